// Round 23
// baseline (203.961 us; speedup 1.0000x reference)
//
#include <hip/hip_runtime.h>
#include <hip/hip_bf16.h>
#include <cstddef>
#include <cstdint>

#define BQ    16
#define CC    384
#define C3    1152
#define HH    56
#define HWP   3136
#define NTOT  (BQ * HWP)   // 50176
#define NHEAD 12
#define HD    32
#define WSZ   7
#define NWIN  64
#define WSQ   49
#define DKS   0.17677669529663687f
#define DKS2  0.2550347251093104f   // DKS * log2(e)

typedef __attribute__((ext_vector_type(8))) short bf16x8;
typedef __attribute__((ext_vector_type(4))) float f32x4;

union U128 { uint4 u; bf16x8 v; ushort us[8]; uint ui[4]; };

__device__ __forceinline__ ushort f2b(float f) {
    __hip_bfloat16 h = __float2bfloat16(f);
    return *reinterpret_cast<ushort*>(&h);
}
__device__ __forceinline__ float b2f(ushort u) {
    __hip_bfloat16 h;
    *reinterpret_cast<ushort*>(&h) = u;
    return __bfloat162float(h);
}

// ---------------------------------------------------------------------------
// Fused prologue: wA1 = bf16(qkv_pw) | wA2 = bf16(out_pw) | M[4][64][64].
// M is PRE-SCALED by log2(e) so attn can use exp2.  (unchanged from r22)
// ---------------------------------------------------------------------------
__global__ void prep_all(const float* __restrict__ qkv_pw,
                         const float* __restrict__ out_pw,
                         const float* __restrict__ pos,
                         ushort* __restrict__ wA1, ushort* __restrict__ wA2,
                         float* __restrict__ M) {
    const int idx = blockIdx.x * 256 + threadIdx.x;
    if (idx < C3 * CC) {
        wA1[idx] = f2b(qkv_pw[idx]);
    } else if (idx < C3 * CC + CC * CC) {
        const int k = idx - C3 * CC;
        wA2[k] = f2b(out_pw[k]);
    } else {
        const int k = idx - C3 * CC - CC * CC;   // [0, 16384)
        const int v = k >> 12, rem = k & 4095;
        const int j = rem >> 6, i = rem & 63;
        float m = -1e30f;
        if (i < WSQ && j < WSQ) {
            const int pir = i / WSZ, pic = i - pir * WSZ;
            const int pjr = j / WSZ, pjc = j - pjr * WSZ;
            const bool msk = ((v & 2) && ((pir >= 4) != (pjr >= 4))) ||
                             ((v & 1) && ((pic >= 4) != (pjc >= 4)));
            m = msk ? -1e30f : pos[(pjr - pir + 6) * 13 + (pjc - pic + 6)] * 1.4426950408889634f;
        }
        M[k] = m;
    }
}

// ---------------------------------------------------------------------------
// roll + depthwise 3x3, pixel-major output [n][384].  (unchanged from r15)
// ---------------------------------------------------------------------------
template <bool BF16IN, int S>
__global__ __launch_bounds__(256) void dconv_px(const void* __restrict__ inv,
                                                const float* __restrict__ dw,
                                                ushort* __restrict__ out) {
    __shared__ ushort pl[6][32][68];
    const int band = blockIdx.x, cg = blockIdx.y, b = blockIdx.z;
    const int i0 = band * 4;
    const int t = threadIdx.x;
    const int ch = t & 31;

    float wreg[9];
    #pragma unroll
    for (int k = 0; k < 9; ++k) wreg[k] = dw[(cg * 32 + ch) * 9 + k];

    if (BF16IN) {
        const ushort* src = (const ushort*)inv;
        const int c8 = t & 3, sc = t >> 2;
        const int cc = sc < 56 ? sc : sc - 56;
        #pragma unroll
        for (int lr = 0; lr < 6; ++lr) {
            const int gi = i0 + lr - 1;
            U128 u; u.u = make_uint4(0, 0, 0, 0);
            if (gi >= 0 && gi < HH) {
                int rr = gi + S; if (rr >= HH) rr -= HH;
                u.u = *(const uint4*)&src[(size_t)(b * HWP + rr * HH + cc) * CC + cg * 32 + c8 * 8];
            }
            #pragma unroll
            for (int k2 = 0; k2 < 8; ++k2) pl[lr][c8 * 8 + k2][sc] = u.us[k2];
        }
    } else {
        const float* src = (const float*)inv;
        const int cq = t & 15, q0 = t >> 4;
        const int scb = cq < 14 ? cq * 4 : cq * 4 - 56;
        #pragma unroll
        for (int k = 0; k < 12; ++k) {
            const int pair = q0 + k * 16;          // 0..191
            const int lc = pair & 31, lr = pair >> 5;
            const int gi = i0 + lr - 1;
            float4 v = make_float4(0.f, 0.f, 0.f, 0.f);
            if (gi >= 0 && gi < HH) {
                int rr = gi + S; if (rr >= HH) rr -= HH;
                v = *(const float4*)&src[((size_t)(b * CC + cg * 32 + lc)) * HWP + rr * HH + scb];
            }
            ushort4 w;
            w.x = f2b(v.x); w.y = f2b(v.y); w.z = f2b(v.z); w.w = f2b(v.w);
            *(ushort4*)&pl[lr][lc][cq * 4] = w;
        }
    }
    __syncthreads();

    const int u = t >> 5;
    #pragma unroll
    for (int iter = 0; iter < 7; ++iter) {
        const int unit = iter * 8 + u;
        const int colb = unit >> 2;
        const int row  = unit & 3;
        const int c0 = colb * 4;
        int sc0 = c0 - 1 + S; if (sc0 >= HH) sc0 -= HH;   // even (S odd, c0 even)
        float acc[4] = {0.f, 0.f, 0.f, 0.f};
        #pragma unroll
        for (int di = 0; di < 3; ++di) {
            const ushort* rp = &pl[row + di][ch][0];
            float v[6];
            #pragma unroll
            for (int k = 0; k < 6; ++k) v[k] = b2f(rp[sc0 + k]);
            if (colb == 0)  v[0] = 0.f;   // image col -1 pad
            if (colb == 13) v[5] = 0.f;   // image col 56 pad
            #pragma unroll
            for (int cc2 = 0; cc2 < 4; ++cc2) {
                acc[cc2] += wreg[di * 3 + 0] * v[cc2];
                acc[cc2] += wreg[di * 3 + 1] * v[cc2 + 1];
                acc[cc2] += wreg[di * 3 + 2] * v[cc2 + 2];
            }
        }
        const int orow = i0 + row;
        #pragma unroll
        for (int cc2 = 0; cc2 < 4; ++cc2)
            out[(size_t)(b * HWP + orow * HH + c0 + cc2) * CC + cg * 32 + ch] = f2b(acc[cc2]);
    }
}

// ---------------------------------------------------------------------------
// pconv1: 128(oc) x 256(n) tile, 512 threads = 8 waves (2x4), BK=32,
// 2-slot double buffer (24 KB/slot: A 8K + B 16K) -> 48 KB, 3 blocks/CU =
// 24 waves/CU (r21 had 12).  Same per-wave work; doubled resident waves
// hide the barrier stall.  vmcnt(3) (3 loads/thread/STAGE).  Two-pass sD
// epilogue (sD[128][136] per n-half).  General bijective XCD swizzle
// (nwg = 1764, nwg%8 = 4).
// ---------------------------------------------------------------------------
__global__ __launch_bounds__(512) void pconv1_mfma(const ushort* __restrict__ bt,
                                                   const ushort* __restrict__ wa,
                                                   const float* __restrict__ bias,
                                                   ushort* __restrict__ outp) {
    __shared__ __align__(16) char smem[49152];   // 2 x (A 8KB + B 16KB); sD overlays

    const int nwg = gridDim.x;                   // 1764
    const int q8 = nwg >> 3, r8 = nwg & 7;
    const int id = blockIdx.x;
    const int xcd = id & 7, off = id >> 3;
    const int wg = (xcd < r8 ? xcd * (q8 + 1) : r8 * (q8 + 1) + (xcd - r8) * q8) + off;
    const int oc0 = (wg % 9) * 128;
    const int n0  = (wg / 9) * 256;

    const int t   = threadIdx.x;
    const int l   = t & 63;
    const int w   = t >> 6;                      // 0..7
    const int wm  = w >> 2, wn = w & 3;          // 2 x 4 waves
    const int i15 = l & 15, g = l >> 4;

    f32x4 acc[4][4] = {};

    // staging: A chunk c = t (rows 0..127); B chunks c = t, c = t+512
    // (rows 0..127 / 128..255).  Physical k-slot c&3 holds logical chunk
    // (c&3)^((row>>1)&3); +512 leaves (c>>3)&3 unchanged (64 mod 4 == 0).
    const int kc = ((t & 3) ^ ((t >> 3) & 3)) * 8;   // pre-swizzled k offset
    const size_t gA0 = (size_t)(oc0 + (t >> 2)) * CC + kc;
    const size_t gB0 = (size_t)(n0 + (t >> 2)) * CC + kc;
    const size_t gB1 = (size_t)(n0 + (t >> 2) + 128) * CC + kc;
    const int ldsOff = w * 1024;                 // wave-uniform base

#define STAGE(buf, k0) do {                                                              \
    char* ba_ = smem + (buf) * 24576;                                                    \
    __builtin_amdgcn_global_load_lds(                                                    \
        (const __attribute__((address_space(1))) void*)(wa + gA0 + (k0)),                \
        (__attribute__((address_space(3))) void*)(ba_ + ldsOff), 16, 0, 0);              \
    __builtin_amdgcn_global_load_lds(                                                    \
        (const __attribute__((address_space(1))) void*)(bt + gB0 + (k0)),                \
        (__attribute__((address_space(3))) void*)(ba_ + 8192 + ldsOff), 16, 0, 0);       \
    __builtin_amdgcn_global_load_lds(                                                    \
        (const __attribute__((address_space(1))) void*)(bt + gB1 + (k0)),                \
        (__attribute__((address_space(3))) void*)(ba_ + 16384 + ldsOff), 16, 0, 0);      \
} while (0)

    // fragment read addressing (same XOR as staging)
    const int colb = (g ^ ((i15 >> 1) & 3)) << 4;
    const int rbA = (wm * 64 + i15) * 64 + colb;     // + i*1024 per fragment
    const int rbB = (wn * 64 + i15) * 64 + colb;     // within 16KB B region

    STAGE(0, 0);
    int cur = 0;
    for (int kt = 0; kt < 12; ++kt) {
        if (kt < 11) {
            STAGE(cur ^ 1, (kt + 1) * 32);
            asm volatile("s_waitcnt vmcnt(3)" ::: "memory");   // tile kt landed
        } else {
            asm volatile("s_waitcnt vmcnt(0)" ::: "memory");
        }
        __builtin_amdgcn_s_barrier();
        const char* bufA = smem + cur * 24576;
        const char* bufB = bufA + 8192;
        bf16x8 a[4], bb[4];
        #pragma unroll
        for (int i = 0; i < 4; ++i) {
            a[i]  = *(const bf16x8*)(bufA + rbA + i * 1024);
            bb[i] = *(const bf16x8*)(bufB + rbB + i * 1024);
        }
        #pragma unroll
        for (int mf = 0; mf < 4; ++mf)
            #pragma unroll
            for (int nf = 0; nf < 4; ++nf)
                acc[mf][nf] = __builtin_amdgcn_mfma_f32_16x16x32_bf16(a[mf], bb[nf], acc[mf][nf], 0, 0, 0);
        __builtin_amdgcn_sched_barrier(0);
        __builtin_amdgcn_s_barrier();
        cur ^= 1;
    }
#undef STAGE

    const int rl = (l >> 4) * 4;   // fragment row base (oc dim)
    const int cl = l & 15;         // fragment col (n dim)
    ushort (* const sD)[136] = (ushort(*)[136])smem;

    __syncthreads();   // all waves done with staging slots before sD overlay
    #pragma unroll
    for (int p = 0; p < 2; ++p) {
        if ((wn >> 1) == p) {
            #pragma unroll
            for (int mf = 0; mf < 4; ++mf) {
                const int ocl = wm * 64 + mf * 16 + rl;
                #pragma unroll
                for (int nf = 0; nf < 4; ++nf) {
                    const int nl = (wn & 1) * 64 + nf * 16 + cl;
                    ushort4 w4;
                    w4.x = f2b(acc[mf][nf][0] + bias[oc0 + ocl + 0]);
                    w4.y = f2b(acc[mf][nf][1] + bias[oc0 + ocl + 1]);
                    w4.z = f2b(acc[mf][nf][2] + bias[oc0 + ocl + 2]);
                    w4.w = f2b(acc[mf][nf][3] + bias[oc0 + ocl + 3]);
                    *(ushort4*)&sD[nl][ocl] = w4;
                }
            }
        }
        __syncthreads();
        #pragma unroll
        for (int rr = 0; rr < 4; ++rr) {
            const int r = (t >> 4) + rr * 32;
            const int c8 = (t & 15) * 8;
            *(uint4*)&outp[(size_t)(n0 + p * 128 + r) * C3 + oc0 + c8] =
                *(const uint4*)&sD[r][c8];
        }
        __syncthreads();
    }
}

// ---------------------------------------------------------------------------
// pconv2 (fp32 NCHW out): r21 3-ring structure, 128x128.  (unchanged)
// ---------------------------------------------------------------------------
__global__ __launch_bounds__(256) void pconv2_mfma(const ushort* __restrict__ bt,
                                                   const ushort* __restrict__ wa,
                                                   const float* __restrict__ bias,
                                                   float* __restrict__ outp) {
    __shared__ __align__(16) char smem[49152];   // 3 x (A 8KB + B 8KB)

    const int nwg = gridDim.x;
    const int cpx = nwg >> 3;
    const int id  = blockIdx.x;
    const int wg  = (id & 7) * cpx + (id >> 3);
    const int oc0 = (wg % (CC / 128)) * 128;
    const int n0  = (wg / (CC / 128)) * 128;

    const int t   = threadIdx.x;
    const int l   = t & 63;
    const int wm  = (t >> 6) >> 1, wn = (t >> 6) & 1;
    const int i15 = l & 15, g = l >> 4;

    f32x4 acc[4][4] = {};

    const int r0 = t >> 2;
    const int kc = ((t & 3) ^ ((t >> 3) & 3)) * 8;   // pre-swizzled k offset
    const size_t gA0 = (size_t)(oc0 + r0) * CC + kc;
    const size_t gA1 = (size_t)(oc0 + r0 + 64) * CC + kc;
    const size_t gB0 = (size_t)(n0 + r0) * CC + kc;
    const size_t gB1 = (size_t)(n0 + r0 + 64) * CC + kc;
    const int ldsOff = (t & 192) * 16;               // wave-uniform base

#define STAGE(buf, k0) do {                                                              \
    char* la_ = smem + (buf) * 16384 + ldsOff;                                           \
    char* lb_ = la_ + 8192;                                                              \
    __builtin_amdgcn_global_load_lds(                                                    \
        (const __attribute__((address_space(1))) void*)(wa + gA0 + (k0)),                \
        (__attribute__((address_space(3))) void*)la_, 16, 0, 0);                         \
    __builtin_amdgcn_global_load_lds(                                                    \
        (const __attribute__((address_space(1))) void*)(wa + gA1 + (k0)),                \
        (__attribute__((address_space(3))) void*)(la_ + 4096), 16, 0, 0);                \
    __builtin_amdgcn_global_load_lds(                                                    \
        (const __attribute__((address_space(1))) void*)(bt + gB0 + (k0)),                \
        (__attribute__((address_space(3))) void*)lb_, 16, 0, 0);                         \
    __builtin_amdgcn_global_load_lds(                                                    \
        (const __attribute__((address_space(1))) void*)(bt + gB1 + (k0)),                \
        (__attribute__((address_space(3))) void*)(lb_ + 4096), 16, 0, 0);                \
} while (0)

    const int colb = (g ^ ((i15 >> 1) & 3)) << 4;
    const int rbA = (wm * 64 + i15) * 64 + colb;
    const int rbB = (wn * 64 + i15) * 64 + colb;

    STAGE(0, 0);
    int slot = 0;
    for (int kt = 0; kt < 12; ++kt) {
        if (kt < 11) {
            const int nslot = (slot == 2) ? 0 : slot + 1;
            STAGE(nslot, (kt + 1) * 32);
            asm volatile("s_waitcnt vmcnt(4)" ::: "memory");
        } else {
            asm volatile("s_waitcnt vmcnt(0)" ::: "memory");
        }
        __builtin_amdgcn_s_barrier();
        const char* bufA = smem + slot * 16384;
        const char* bufB = bufA + 8192;
        bf16x8 a[4], bb[4];
        #pragma unroll
        for (int i = 0; i < 4; ++i) {
            a[i]  = *(const bf16x8*)(bufA + rbA + i * 1024);
            bb[i] = *(const bf16x8*)(bufB + rbB + i * 1024);
        }
        #pragma unroll
        for (int mf = 0; mf < 4; ++mf)
            #pragma unroll
            for (int nf = 0; nf < 4; ++nf)
                acc[mf][nf] = __builtin_amdgcn_mfma_f32_16x16x32_bf16(a[mf], bb[nf], acc[mf][nf], 0, 0, 0);
        slot = (slot == 2) ? 0 : slot + 1;
    }
#undef STAGE

    const int rl = (l >> 4) * 4;
    const int cl = l & 15;
    #pragma unroll
    for (int mf = 0; mf < 4; ++mf) {
        const int row = oc0 + wm * 64 + mf * 16 + rl;
        #pragma unroll
        for (int r = 0; r < 4; ++r) {
            const float bs = bias[row + r];
            #pragma unroll
            for (int nf = 0; nf < 4; ++nf) {
                const int n = n0 + wn * 64 + nf * 16 + cl;
                const int b = n / HWP, p = n - b * HWP;
                outp[((size_t)b * CC + row + r) * HWP + p] = acc[mf][nf][r] + bs;
            }
        }
    }
}

// ---------------------------------------------------------------------------
// MFMA windowed attention, P in registers, M-fold, no-max exp2 softmax,
// 1 wave per block, setprio around MFMA clusters.  (unchanged from r22)
// ---------------------------------------------------------------------------
__global__ __launch_bounds__(64) void attn_mfma(const ushort* __restrict__ qkv,
                                                const float* __restrict__ M,
                                                ushort* __restrict__ out) {
    __shared__ __align__(16) ushort sVw[64 * 40];   // V, then O bounce

    const int w = blockIdx.x, h = blockIdx.y, b = blockIdx.z;
    const int wr = w >> 3, wc = w & 7;
    const int l = threadIdx.x;
    const int i15 = l & 15, g = l >> 4;
    const int hch = h * HD;
    const float* __restrict__ Mv = M + ((((wr == 7) ? 2 : 0) | ((wc == 7) ? 1 : 0)) << 12);

    #pragma unroll
    for (int pass = 0; pass < 4; ++pass) {
        const int e = l + pass * 64;
        const int pix = e >> 2, c8 = e & 3;
        uint4 v = make_uint4(0, 0, 0, 0);
        if (pix < WSQ) {
            const int n = b * HWP + (wr * WSZ + pix / 7) * HH + wc * WSZ + pix % 7;
            v = *(const uint4*)&qkv[(size_t)n * C3 + 2 * CC + hch + c8 * 8];
        }
        const int cst = c8 ^ ((pix >> 2) & 3);
        *(uint4*)&sVw[pix * 40 + cst * 8] = v;
    }

    bf16x8 qf[4], kf[4];
    #pragma unroll
    for (int it = 0; it < 4; ++it) {
        const int i = it * 16 + i15;
        U128 uq, uk;
        uq.u = make_uint4(0, 0, 0, 0);
        uk.u = make_uint4(0, 0, 0, 0);
        if (i < WSQ) {
            const int n = b * HWP + (wr * WSZ + i / 7) * HH + wc * WSZ + i % 7;
            uq.u = *(const uint4*)&qkv[(size_t)n * C3 + hch + g * 8];
            uk.u = *(const uint4*)&qkv[(size_t)n * C3 + CC + hch + g * 8];
        }
        qf[it] = uq.v;
        kf[it] = uk.v;
    }

    f32x4 sS[4][4] = {};
    __builtin_amdgcn_s_setprio(1);
    #pragma unroll
    for (int jt = 0; jt < 4; ++jt)
        #pragma unroll
        for (int it = 0; it < 4; ++it)
            sS[jt][it] = __builtin_amdgcn_mfma_f32_16x16x32_bf16(kf[jt], qf[it], sS[jt][it], 0, 0, 0);
    __builtin_amdgcn_s_setprio(0);

    #pragma unroll
    for (int jt = 0; jt < 4; ++jt) {
        #pragma unroll
        for (int r = 0; r < 4; ++r) {
            const float* mrow = Mv + (jt * 16 + 4 * g + r) * 64 + i15;
            #pragma unroll
            for (int it = 0; it < 4; ++it)
                sS[jt][it][r] = fmaf(sS[jt][it][r], DKS2, mrow[it * 16]);
        }
    }

    #pragma unroll
    for (int it = 0; it < 4; ++it) {
        float sum = 0.f;
        #pragma unroll
        for (int jt = 0; jt < 4; ++jt)
            #pragma unroll
            for (int r = 0; r < 4; ++r) {
                const float e2 = exp2f(sS[jt][it][r]);
                sS[jt][it][r] = e2;
                sum += e2;
            }
        sum += __shfl_xor(sum, 16);
        sum += __shfl_xor(sum, 32);
        const float inv = 1.f / sum;
        #pragma unroll
        for (int jt = 0; jt < 4; ++jt)
            #pragma unroll
            for (int r = 0; r < 4; ++r) sS[jt][it][r] *= inv;
    }

    uint plo[4][4], phi[4][4];     // [it][jt]; covers j = jt*16+4g+{0,1}/{2,3}
    #pragma unroll
    for (int it = 0; it < 4; ++it)
        #pragma unroll
        for (int jt = 0; jt < 4; ++jt) {
            plo[it][jt] = (uint)f2b(sS[jt][it][0]) | ((uint)f2b(sS[jt][it][1]) << 16);
            phi[it][jt] = (uint)f2b(sS[jt][it][2]) | ((uint)f2b(sS[jt][it][3]) << 16);
        }

    const int srcLo = (2 * (g & 1)) * 16 + i15;
    const int srcHi = srcLo + 16;
    const bool oddHalf = ((g >> 1) & 1) != 0;

    f32x4 oacc[4][2] = {};
    #pragma unroll
    for (int kt = 0; kt < 2; ++kt) {
        bf16x8 bv[2];
        #pragma unroll
        for (int nt = 0; nt < 2; ++nt) {
            U128 u;
            #pragma unroll
            for (int s = 0; s < 8; ++s) {
                const int j = kt * 32 + 8 * g + s;
                const int d = nt * 16 + i15;
                const int cp = (d >> 3) ^ ((j >> 2) & 3);
                u.us[s] = sVw[j * 40 + cp * 8 + (d & 7)];
            }
            bv[nt] = u.v;
        }
        __builtin_amdgcn_s_setprio(1);
        #pragma unroll
        for (int mt = 0; mt < 4; ++mt) {
            U128 pu;
            #pragma unroll
            for (int u2 = 0; u2 < 4; ++u2) {
                const int sl = (u2 >> 1) ? srcHi : srcLo;
                const uint vE = __shfl((u2 & 1) ? phi[mt][2 * kt]     : plo[mt][2 * kt],     sl, 64);
                const uint vO = __shfl((u2 & 1) ? phi[mt][2 * kt + 1] : plo[mt][2 * kt + 1], sl, 64);
                pu.ui[u2] = oddHalf ? vO : vE;
            }
            #pragma unroll
            for (int nt = 0; nt < 2; ++nt)
                oacc[mt][nt] = __builtin_amdgcn_mfma_f32_16x16x32_bf16(pu.v, bv[nt], oacc[mt][nt], 0, 0, 0);
        }
        __builtin_amdgcn_s_setprio(0);
    }

    #pragma unroll
    for (int mt = 0; mt < 4; ++mt)
        #pragma unroll
        for (int nt = 0; nt < 2; ++nt)
            #pragma unroll
            for (int r = 0; r < 4; ++r) {
                const int i = mt * 16 + 4 * g + r;
                const int d = nt * 16 + i15;
                const int cp = (d >> 3) ^ ((i >> 2) & 3);
                sVw[i * 40 + cp * 8 + (d & 7)] = f2b(oacc[mt][nt][r]);
            }

    #pragma unroll
    for (int pass = 0; pass < 4; ++pass) {
        const int e = l + pass * 64;
        const int pix = e >> 2, c8 = e & 3;
        if (pix < WSQ) {
            const int n = b * HWP + (wr * WSZ + pix / 7) * HH + wc * WSZ + pix % 7;
            const int cp = c8 ^ ((pix >> 2) & 3);
            *(uint4*)&out[(size_t)n * CC + hch + c8 * 8] = *(const uint4*)&sVw[pix * 40 + cp * 8];
        }
    }
}

// ---------------------------------------------------------------------------
extern "C" void kernel_launch(void* const* d_in, const int* in_sizes, int n_in,
                              void* d_out, int out_size, void* d_ws, size_t ws_size,
                              hipStream_t stream) {
    const float* x      = (const float*)d_in[0];
    const float* qkv_dw = (const float*)d_in[1];
    const float* qkv_pw = (const float*)d_in[2];
    const float* qkv_pb = (const float*)d_in[3];
    const float* out_dw = (const float*)d_in[4];
    const float* out_pw = (const float*)d_in[5];
    const float* out_pb = (const float*)d_in[6];
    const float* pos    = (const float*)d_in[7];

    // ws: A [NTOT][384] | B [NTOT][1152] | wA1 [1152][384] | wA2 [384][384] | M[4][64][64] f32
    ushort* A   = (ushort*)d_ws;
    ushort* B   = A + (size_t)NTOT * CC;
    ushort* wA1 = B + (size_t)NTOT * C3;
    ushort* wA2 = wA1 + (size_t)C3 * CC;
    float*  Mw  = (float*)(wA2 + (size_t)CC * CC);

    // 0) fused prologue (weight casts + log2e-scaled mask matrix)
    prep_all<<<2368, 256, 0, stream>>>(qkv_pw, out_pw, pos, wA1, wA2, Mw);

    // 1) roll(-3) + depthwise -> A [n][384] bf16
    dconv_px<false, 3><<<dim3(14, 12, BQ), 256, 0, stream>>>(x, qkv_dw, A);
    // 2) pointwise 384->1152 -> B [n][1152] bf16  (128x256 tile, 8 waves)
    pconv1_mfma<<<dim3(9 * (NTOT / 256)), 512, 0, stream>>>(A, wA1, qkv_pb, B);
    // 3) windowed attention -> A [n][384] bf16  (1 wave per (window,head))
    attn_mfma<<<dim3(NWIN, NHEAD, BQ), 64, 0, stream>>>(B, Mw, A);
    // 4) roll(+3) + depthwise -> B (reused) [n][384] bf16
    dconv_px<true, 53><<<dim3(14, 12, BQ), 256, 0, stream>>>(A, out_dw, B);
    // 5) pointwise 384->384 -> d_out fp32 NCHW
    pconv2_mfma<<<dim3((CC / 128) * (NTOT / 128)), 256, 0, stream>>>(B, wA2, out_pb, (float*)d_out);
}

// Round 24
// 192.613 us; speedup vs baseline: 1.0589x; 1.0589x over previous
//
#include <hip/hip_runtime.h>
#include <hip/hip_bf16.h>
#include <cstddef>
#include <cstdint>

#define BQ    16
#define CC    384
#define C3    1152
#define HH    56
#define HWP   3136
#define NTOT  (BQ * HWP)   // 50176
#define NHEAD 12
#define HD    32
#define WSZ   7
#define NWIN  64
#define WSQ   49
#define DKS   0.17677669529663687f
#define DKS2  0.2550347251093104f   // DKS * log2(e)

typedef __attribute__((ext_vector_type(8))) short bf16x8;
typedef __attribute__((ext_vector_type(4))) float f32x4;

union U128 { uint4 u; bf16x8 v; ushort us[8]; uint ui[4]; };

__device__ __forceinline__ ushort f2b(float f) {
    __hip_bfloat16 h = __float2bfloat16(f);
    return *reinterpret_cast<ushort*>(&h);
}
__device__ __forceinline__ float b2f(ushort u) {
    __hip_bfloat16 h;
    *reinterpret_cast<ushort*>(&h) = u;
    return __bfloat162float(h);
}

// ---------------------------------------------------------------------------
// Fused prologue: wA1 = bf16(qkv_pw) | wA2 = bf16(out_pw) | M[4][64][64].
// M is PRE-SCALED by log2(e) so attn can use exp2.  (unchanged from r22)
// ---------------------------------------------------------------------------
__global__ void prep_all(const float* __restrict__ qkv_pw,
                         const float* __restrict__ out_pw,
                         const float* __restrict__ pos,
                         ushort* __restrict__ wA1, ushort* __restrict__ wA2,
                         float* __restrict__ M) {
    const int idx = blockIdx.x * 256 + threadIdx.x;
    if (idx < C3 * CC) {
        wA1[idx] = f2b(qkv_pw[idx]);
    } else if (idx < C3 * CC + CC * CC) {
        const int k = idx - C3 * CC;
        wA2[k] = f2b(out_pw[k]);
    } else {
        const int k = idx - C3 * CC - CC * CC;   // [0, 16384)
        const int v = k >> 12, rem = k & 4095;
        const int j = rem >> 6, i = rem & 63;
        float m = -1e30f;
        if (i < WSQ && j < WSQ) {
            const int pir = i / WSZ, pic = i - pir * WSZ;
            const int pjr = j / WSZ, pjc = j - pjr * WSZ;
            const bool msk = ((v & 2) && ((pir >= 4) != (pjr >= 4))) ||
                             ((v & 1) && ((pic >= 4) != (pjc >= 4)));
            m = msk ? -1e30f : pos[(pjr - pir + 6) * 13 + (pjc - pic + 6)] * 1.4426950408889634f;
        }
        M[k] = m;
    }
}

// ---------------------------------------------------------------------------
// roll + depthwise 3x3, pixel-major output [n][384].  (unchanged from r15)
// ---------------------------------------------------------------------------
template <bool BF16IN, int S>
__global__ __launch_bounds__(256) void dconv_px(const void* __restrict__ inv,
                                                const float* __restrict__ dw,
                                                ushort* __restrict__ out) {
    __shared__ ushort pl[6][32][68];
    const int band = blockIdx.x, cg = blockIdx.y, b = blockIdx.z;
    const int i0 = band * 4;
    const int t = threadIdx.x;
    const int ch = t & 31;

    float wreg[9];
    #pragma unroll
    for (int k = 0; k < 9; ++k) wreg[k] = dw[(cg * 32 + ch) * 9 + k];

    if (BF16IN) {
        const ushort* src = (const ushort*)inv;
        const int c8 = t & 3, sc = t >> 2;
        const int cc = sc < 56 ? sc : sc - 56;
        #pragma unroll
        for (int lr = 0; lr < 6; ++lr) {
            const int gi = i0 + lr - 1;
            U128 u; u.u = make_uint4(0, 0, 0, 0);
            if (gi >= 0 && gi < HH) {
                int rr = gi + S; if (rr >= HH) rr -= HH;
                u.u = *(const uint4*)&src[(size_t)(b * HWP + rr * HH + cc) * CC + cg * 32 + c8 * 8];
            }
            #pragma unroll
            for (int k2 = 0; k2 < 8; ++k2) pl[lr][c8 * 8 + k2][sc] = u.us[k2];
        }
    } else {
        const float* src = (const float*)inv;
        const int cq = t & 15, q0 = t >> 4;
        const int scb = cq < 14 ? cq * 4 : cq * 4 - 56;
        #pragma unroll
        for (int k = 0; k < 12; ++k) {
            const int pair = q0 + k * 16;          // 0..191
            const int lc = pair & 31, lr = pair >> 5;
            const int gi = i0 + lr - 1;
            float4 v = make_float4(0.f, 0.f, 0.f, 0.f);
            if (gi >= 0 && gi < HH) {
                int rr = gi + S; if (rr >= HH) rr -= HH;
                v = *(const float4*)&src[((size_t)(b * CC + cg * 32 + lc)) * HWP + rr * HH + scb];
            }
            ushort4 w;
            w.x = f2b(v.x); w.y = f2b(v.y); w.z = f2b(v.z); w.w = f2b(v.w);
            *(ushort4*)&pl[lr][lc][cq * 4] = w;
        }
    }
    __syncthreads();

    const int u = t >> 5;
    #pragma unroll
    for (int iter = 0; iter < 7; ++iter) {
        const int unit = iter * 8 + u;
        const int colb = unit >> 2;
        const int row  = unit & 3;
        const int c0 = colb * 4;
        int sc0 = c0 - 1 + S; if (sc0 >= HH) sc0 -= HH;   // even (S odd, c0 even)
        float acc[4] = {0.f, 0.f, 0.f, 0.f};
        #pragma unroll
        for (int di = 0; di < 3; ++di) {
            const ushort* rp = &pl[row + di][ch][0];
            float v[6];
            #pragma unroll
            for (int k = 0; k < 6; ++k) v[k] = b2f(rp[sc0 + k]);
            if (colb == 0)  v[0] = 0.f;   // image col -1 pad
            if (colb == 13) v[5] = 0.f;   // image col 56 pad
            #pragma unroll
            for (int cc2 = 0; cc2 < 4; ++cc2) {
                acc[cc2] += wreg[di * 3 + 0] * v[cc2];
                acc[cc2] += wreg[di * 3 + 1] * v[cc2 + 1];
                acc[cc2] += wreg[di * 3 + 2] * v[cc2 + 2];
            }
        }
        const int orow = i0 + row;
        #pragma unroll
        for (int cc2 = 0; cc2 < 4; ++cc2)
            out[(size_t)(b * HWP + orow * HH + c0 + cc2) * CC + cg * 32 + ch] = f2b(acc[cc2]);
    }
}

// ---------------------------------------------------------------------------
// MFMA GEMM.  (r21/r22 best-measured: 3-deep ring, 1 barrier/K-step,
// vmcnt(4), XOR swizzle, XCD-chunk-swizzled 1-D grid — 67.5 us)
// ---------------------------------------------------------------------------
template <int OC, bool OUT_BF16>
__global__ __launch_bounds__(256) void pconv_mfma(const ushort* __restrict__ bt,
                                                  const ushort* __restrict__ wa,
                                                  const float* __restrict__ bias,
                                                  void* __restrict__ outv) {
    __shared__ __align__(16) char smem[49152];   // 3 x (A 8KB + B 8KB); sD overlays

    const int nwg = gridDim.x;
    const int cpx = nwg >> 3;
    const int id  = blockIdx.x;
    const int wg  = (id & 7) * cpx + (id >> 3);
    const int oc0 = (wg % (OC / 128)) * 128;
    const int n0  = (wg / (OC / 128)) * 128;

    const int t   = threadIdx.x;
    const int l   = t & 63;
    const int wm  = (t >> 6) >> 1, wn = (t >> 6) & 1;
    const int i15 = l & 15, g = l >> 4;

    f32x4 acc[4][4] = {};

    const int r0 = t >> 2;
    const int kc = ((t & 3) ^ ((t >> 3) & 3)) * 8;   // pre-swizzled k offset
    const size_t gA0 = (size_t)(oc0 + r0) * CC + kc;
    const size_t gA1 = (size_t)(oc0 + r0 + 64) * CC + kc;
    const size_t gB0 = (size_t)(n0 + r0) * CC + kc;
    const size_t gB1 = (size_t)(n0 + r0 + 64) * CC + kc;
    const int ldsOff = (t & 192) * 16;               // wave-uniform base

#define STAGE(buf, k0) do {                                                              \
    char* la_ = smem + (buf) * 16384 + ldsOff;                                           \
    char* lb_ = la_ + 8192;                                                              \
    __builtin_amdgcn_global_load_lds(                                                    \
        (const __attribute__((address_space(1))) void*)(wa + gA0 + (k0)),                \
        (__attribute__((address_space(3))) void*)la_, 16, 0, 0);                         \
    __builtin_amdgcn_global_load_lds(                                                    \
        (const __attribute__((address_space(1))) void*)(wa + gA1 + (k0)),                \
        (__attribute__((address_space(3))) void*)(la_ + 4096), 16, 0, 0);                \
    __builtin_amdgcn_global_load_lds(                                                    \
        (const __attribute__((address_space(1))) void*)(bt + gB0 + (k0)),                \
        (__attribute__((address_space(3))) void*)lb_, 16, 0, 0);                         \
    __builtin_amdgcn_global_load_lds(                                                    \
        (const __attribute__((address_space(1))) void*)(bt + gB1 + (k0)),                \
        (__attribute__((address_space(3))) void*)(lb_ + 4096), 16, 0, 0);                \
} while (0)

    const int colb = (g ^ ((i15 >> 1) & 3)) << 4;
    const int rbA = (wm * 64 + i15) * 64 + colb;     // + i*1024 per fragment
    const int rbB = (wn * 64 + i15) * 64 + colb;

    STAGE(0, 0);
    int slot = 0;
    for (int kt = 0; kt < 12; ++kt) {
        if (kt < 11) {
            const int nslot = (slot == 2) ? 0 : slot + 1;
            STAGE(nslot, (kt + 1) * 32);
            asm volatile("s_waitcnt vmcnt(4)" ::: "memory");   // tile kt landed
        } else {
            asm volatile("s_waitcnt vmcnt(0)" ::: "memory");
        }
        __builtin_amdgcn_s_barrier();
        const char* bufA = smem + slot * 16384;
        const char* bufB = bufA + 8192;
        bf16x8 a[4], bb[4];
        #pragma unroll
        for (int i = 0; i < 4; ++i) {
            a[i]  = *(const bf16x8*)(bufA + rbA + i * 1024);
            bb[i] = *(const bf16x8*)(bufB + rbB + i * 1024);
        }
        #pragma unroll
        for (int mf = 0; mf < 4; ++mf)
            #pragma unroll
            for (int nf = 0; nf < 4; ++nf)
                acc[mf][nf] = __builtin_amdgcn_mfma_f32_16x16x32_bf16(a[mf], bb[nf], acc[mf][nf], 0, 0, 0);
        slot = (slot == 2) ? 0 : slot + 1;
    }
#undef STAGE

    const int rl = (l >> 4) * 4;
    const int cl = l & 15;
    if (OUT_BF16) {
        __syncthreads();   // all waves done reading the ring before sD overlay
        ushort (* const sD)[136] = (ushort(*)[136])smem;
        #pragma unroll
        for (int mf = 0; mf < 4; ++mf) {
            const int ocl = wm * 64 + mf * 16 + rl;
            #pragma unroll
            for (int nf = 0; nf < 4; ++nf) {
                const int nl = wn * 64 + nf * 16 + cl;
                ushort4 w4;
                w4.x = f2b(acc[mf][nf][0] + bias[oc0 + ocl + 0]);
                w4.y = f2b(acc[mf][nf][1] + bias[oc0 + ocl + 1]);
                w4.z = f2b(acc[mf][nf][2] + bias[oc0 + ocl + 2]);
                w4.w = f2b(acc[mf][nf][3] + bias[oc0 + ocl + 3]);
                *(ushort4*)&sD[nl][ocl] = w4;
            }
        }
        __syncthreads();
        ushort* outp = (ushort*)outv;
        #pragma unroll
        for (int rr = 0; rr < 8; ++rr) {
            const int r = (t >> 4) + rr * 16;
            const int c8 = (t & 15) * 8;
            *(uint4*)&outp[(size_t)(n0 + r) * C3 + oc0 + c8] = *(const uint4*)&sD[r][c8];
        }
    } else {
        float* outp = (float*)outv;
        #pragma unroll
        for (int mf = 0; mf < 4; ++mf) {
            const int row = oc0 + wm * 64 + mf * 16 + rl;
            #pragma unroll
            for (int r = 0; r < 4; ++r) {
                const float bs = bias[row + r];
                #pragma unroll
                for (int nf = 0; nf < 4; ++nf) {
                    const int n = n0 + wn * 64 + nf * 16 + cl;
                    const int b = n / HWP, p = n - b * HWP;
                    outp[((size_t)b * OC + row + r) * HWP + p] = acc[mf][nf][r] + bs;
                }
            }
        }
    }
}

// ---------------------------------------------------------------------------
// MFMA windowed attention, P in registers, M-fold, no-max exp2 softmax,
// 1 wave per block, setprio around MFMA clusters.  (unchanged from r22)
// ---------------------------------------------------------------------------
__global__ __launch_bounds__(64) void attn_mfma(const ushort* __restrict__ qkv,
                                                const float* __restrict__ M,
                                                ushort* __restrict__ out) {
    __shared__ __align__(16) ushort sVw[64 * 40];   // V, then O bounce

    const int w = blockIdx.x, h = blockIdx.y, b = blockIdx.z;
    const int wr = w >> 3, wc = w & 7;
    const int l = threadIdx.x;
    const int i15 = l & 15, g = l >> 4;
    const int hch = h * HD;
    const float* __restrict__ Mv = M + ((((wr == 7) ? 2 : 0) | ((wc == 7) ? 1 : 0)) << 12);

    #pragma unroll
    for (int pass = 0; pass < 4; ++pass) {
        const int e = l + pass * 64;
        const int pix = e >> 2, c8 = e & 3;
        uint4 v = make_uint4(0, 0, 0, 0);
        if (pix < WSQ) {
            const int n = b * HWP + (wr * WSZ + pix / 7) * HH + wc * WSZ + pix % 7;
            v = *(const uint4*)&qkv[(size_t)n * C3 + 2 * CC + hch + c8 * 8];
        }
        const int cst = c8 ^ ((pix >> 2) & 3);
        *(uint4*)&sVw[pix * 40 + cst * 8] = v;
    }

    bf16x8 qf[4], kf[4];
    #pragma unroll
    for (int it = 0; it < 4; ++it) {
        const int i = it * 16 + i15;
        U128 uq, uk;
        uq.u = make_uint4(0, 0, 0, 0);
        uk.u = make_uint4(0, 0, 0, 0);
        if (i < WSQ) {
            const int n = b * HWP + (wr * WSZ + i / 7) * HH + wc * WSZ + i % 7;
            uq.u = *(const uint4*)&qkv[(size_t)n * C3 + hch + g * 8];
            uk.u = *(const uint4*)&qkv[(size_t)n * C3 + CC + hch + g * 8];
        }
        qf[it] = uq.v;
        kf[it] = uk.v;
    }

    f32x4 sS[4][4] = {};
    __builtin_amdgcn_s_setprio(1);
    #pragma unroll
    for (int jt = 0; jt < 4; ++jt)
        #pragma unroll
        for (int it = 0; it < 4; ++it)
            sS[jt][it] = __builtin_amdgcn_mfma_f32_16x16x32_bf16(kf[jt], qf[it], sS[jt][it], 0, 0, 0);
    __builtin_amdgcn_s_setprio(0);

    #pragma unroll
    for (int jt = 0; jt < 4; ++jt) {
        #pragma unroll
        for (int r = 0; r < 4; ++r) {
            const float* mrow = Mv + (jt * 16 + 4 * g + r) * 64 + i15;
            #pragma unroll
            for (int it = 0; it < 4; ++it)
                sS[jt][it][r] = fmaf(sS[jt][it][r], DKS2, mrow[it * 16]);
        }
    }

    #pragma unroll
    for (int it = 0; it < 4; ++it) {
        float sum = 0.f;
        #pragma unroll
        for (int jt = 0; jt < 4; ++jt)
            #pragma unroll
            for (int r = 0; r < 4; ++r) {
                const float e2 = exp2f(sS[jt][it][r]);
                sS[jt][it][r] = e2;
                sum += e2;
            }
        sum += __shfl_xor(sum, 16);
        sum += __shfl_xor(sum, 32);
        const float inv = 1.f / sum;
        #pragma unroll
        for (int jt = 0; jt < 4; ++jt)
            #pragma unroll
            for (int r = 0; r < 4; ++r) sS[jt][it][r] *= inv;
    }

    uint plo[4][4], phi[4][4];     // [it][jt]; covers j = jt*16+4g+{0,1}/{2,3}
    #pragma unroll
    for (int it = 0; it < 4; ++it)
        #pragma unroll
        for (int jt = 0; jt < 4; ++jt) {
            plo[it][jt] = (uint)f2b(sS[jt][it][0]) | ((uint)f2b(sS[jt][it][1]) << 16);
            phi[it][jt] = (uint)f2b(sS[jt][it][2]) | ((uint)f2b(sS[jt][it][3]) << 16);
        }

    const int srcLo = (2 * (g & 1)) * 16 + i15;
    const int srcHi = srcLo + 16;
    const bool oddHalf = ((g >> 1) & 1) != 0;

    f32x4 oacc[4][2] = {};
    #pragma unroll
    for (int kt = 0; kt < 2; ++kt) {
        bf16x8 bv[2];
        #pragma unroll
        for (int nt = 0; nt < 2; ++nt) {
            U128 u;
            #pragma unroll
            for (int s = 0; s < 8; ++s) {
                const int j = kt * 32 + 8 * g + s;
                const int d = nt * 16 + i15;
                const int cp = (d >> 3) ^ ((j >> 2) & 3);
                u.us[s] = sVw[j * 40 + cp * 8 + (d & 7)];
            }
            bv[nt] = u.v;
        }
        __builtin_amdgcn_s_setprio(1);
        #pragma unroll
        for (int mt = 0; mt < 4; ++mt) {
            U128 pu;
            #pragma unroll
            for (int u2 = 0; u2 < 4; ++u2) {
                const int sl = (u2 >> 1) ? srcHi : srcLo;
                const uint vE = __shfl((u2 & 1) ? phi[mt][2 * kt]     : plo[mt][2 * kt],     sl, 64);
                const uint vO = __shfl((u2 & 1) ? phi[mt][2 * kt + 1] : plo[mt][2 * kt + 1], sl, 64);
                pu.ui[u2] = oddHalf ? vO : vE;
            }
            #pragma unroll
            for (int nt = 0; nt < 2; ++nt)
                oacc[mt][nt] = __builtin_amdgcn_mfma_f32_16x16x32_bf16(pu.v, bv[nt], oacc[mt][nt], 0, 0, 0);
        }
        __builtin_amdgcn_s_setprio(0);
    }

    #pragma unroll
    for (int mt = 0; mt < 4; ++mt)
        #pragma unroll
        for (int nt = 0; nt < 2; ++nt)
            #pragma unroll
            for (int r = 0; r < 4; ++r) {
                const int i = mt * 16 + 4 * g + r;
                const int d = nt * 16 + i15;
                const int cp = (d >> 3) ^ ((i >> 2) & 3);
                sVw[i * 40 + cp * 8 + (d & 7)] = f2b(oacc[mt][nt][r]);
            }

    #pragma unroll
    for (int pass = 0; pass < 4; ++pass) {
        const int e = l + pass * 64;
        const int pix = e >> 2, c8 = e & 3;
        if (pix < WSQ) {
            const int n = b * HWP + (wr * WSZ + pix / 7) * HH + wc * WSZ + pix % 7;
            const int cp = c8 ^ ((pix >> 2) & 3);
            *(uint4*)&out[(size_t)n * CC + hch + c8 * 8] = *(const uint4*)&sVw[pix * 40 + cp * 8];
        }
    }
}

// ---------------------------------------------------------------------------
extern "C" void kernel_launch(void* const* d_in, const int* in_sizes, int n_in,
                              void* d_out, int out_size, void* d_ws, size_t ws_size,
                              hipStream_t stream) {
    const float* x      = (const float*)d_in[0];
    const float* qkv_dw = (const float*)d_in[1];
    const float* qkv_pw = (const float*)d_in[2];
    const float* qkv_pb = (const float*)d_in[3];
    const float* out_dw = (const float*)d_in[4];
    const float* out_pw = (const float*)d_in[5];
    const float* out_pb = (const float*)d_in[6];
    const float* pos    = (const float*)d_in[7];

    // ws: A [NTOT][384] | B [NTOT][1152] | wA1 [1152][384] | wA2 [384][384] | M[4][64][64] f32
    ushort* A   = (ushort*)d_ws;
    ushort* B   = A + (size_t)NTOT * CC;
    ushort* wA1 = B + (size_t)NTOT * C3;
    ushort* wA2 = wA1 + (size_t)C3 * CC;
    float*  Mw  = (float*)(wA2 + (size_t)CC * CC);

    // 0) fused prologue (weight casts + log2e-scaled mask matrix)
    prep_all<<<2368, 256, 0, stream>>>(qkv_pw, out_pw, pos, wA1, wA2, Mw);

    // 1) roll(-3) + depthwise -> A [n][384] bf16
    dconv_px<false, 3><<<dim3(14, 12, BQ), 256, 0, stream>>>(x, qkv_dw, A);
    // 2) pointwise 384->1152 -> B [n][1152] bf16  (XCD-swizzled 1-D grid)
    pconv_mfma<C3, true><<<dim3((C3 / 128) * (NTOT / 128)), 256, 0, stream>>>(A, wA1, qkv_pb, B);
    // 3) windowed attention -> A [n][384] bf16  (1 wave per (window,head))
    attn_mfma<<<dim3(NWIN, NHEAD, BQ), 64, 0, stream>>>(B, Mw, A);
    // 4) roll(+3) + depthwise -> B (reused) [n][384] bf16
    dconv_px<true, 53><<<dim3(14, 12, BQ), 256, 0, stream>>>(A, out_dw, B);
    // 5) pointwise 384->384 -> d_out fp32 NCHW  (XCD-swizzled 1-D grid)
    pconv_mfma<CC, false><<<dim3((CC / 128) * (NTOT / 128)), 256, 0, stream>>>(B, wA2, out_pb, (float*)d_out);
}